// Round 25
// baseline (110.785 us; speedup 1.0000x reference)
//
#include <hip/hip_runtime.h>
#include <hip/hip_bf16.h>
#include <hip/hip_fp16.h>

typedef _Float16 half8 __attribute__((ext_vector_type(8)));
typedef float floatx4 __attribute__((ext_vector_type(4)));
typedef unsigned short u16;
typedef unsigned int u32;
typedef unsigned long long u64;

#define LEAKY 0.2f
#define MASKV -9.0e15f

// ---------------- Kernel A: h_ds[b][d] = (mean of 150 rows) @ wd ----------------
__global__ __launch_bounds__(256) void k_hds(const float* __restrict__ hl,
                                             const float* __restrict__ ht,
                                             const float* __restrict__ ie,
                                             const float* __restrict__ wd,
                                             float* __restrict__ hds) {
  int b = blockIdx.x, tid = threadIdx.x;
  int d = tid & 127, hh = tid >> 7;
  __shared__ float pa_[2][128];
  __shared__ float ml[128];
  __shared__ float pb_[2][128];
  const size_t base = (size_t)b * 50 * 128 + d;
  float acc = 0.f;
  for (int r = hh * 25; r < hh * 25 + 25; ++r) {
    size_t o = base + (size_t)r * 128;
    acc += hl[o] + ht[o] + ie[o];
  }
  pa_[hh][d] = acc;
  __syncthreads();
  if (hh == 0) ml[d] = (pa_[0][d] + pa_[1][d]) * (1.0f / 150.0f);
  __syncthreads();
  float o = 0.f;
  for (int k = hh * 64; k < hh * 64 + 64; ++k) o = fmaf(ml[k], wd[k * 128 + d], o);
  pb_[hh][d] = o;
  __syncthreads();
  if (hh == 0) hds[b * 128 + d] = pb_[0][d] + pb_[1][d];
}

// ---------------- Kernel B: s[w][b][i], h16[b][i][d], h16T[b][d][i] ----------------
__global__ __launch_bounds__(256) void k_prep(const float* __restrict__ h,
                                              const float* __restrict__ hds,
                                              const float* __restrict__ a0,
                                              const float* __restrict__ a1,
                                              const float* __restrict__ a2,
                                              const float* __restrict__ a3,
                                              float* __restrict__ s,
                                              u16* __restrict__ h16,
                                              u16* __restrict__ h16T) {
  int b = blockIdx.x >> 3, i0 = (blockIdx.x & 7) * 64;
  int tid = threadIdx.x, w = tid >> 6, l = tid & 63;
  __shared__ u16 tile[64][130];
  int d0 = 2 * l;
  float2 hd2 = *(const float2*)(hds + b * 128 + d0);
  float2 av0 = *(const float2*)(a0 + d0);
  float2 av1 = *(const float2*)(a1 + d0);
  float2 av2 = *(const float2*)(a2 + d0);
  float2 av3 = *(const float2*)(a3 + d0);
  for (int rr = 0; rr < 16; ++rr) {
    int il = rr * 4 + w;
    size_t row = (size_t)b * 512 + i0 + il;
    float2 hv = *(const float2*)(h + row * 128 + d0);
    _Float16 f0 = (_Float16)hv.x, f1 = (_Float16)hv.y;
    u16 u0 = __builtin_bit_cast(u16, f0), u1 = __builtin_bit_cast(u16, f1);
    tile[il][d0] = u0;
    tile[il][d0 + 1] = u1;
    *(u32*)(h16 + row * 128 + d0) = (u32)u0 | ((u32)u1 << 16);
    float t0 = hv.x * hd2.x, t1 = hv.y * hd2.y;
    float p0 = t0 * av0.x + t1 * av0.y;
    float p1 = t0 * av1.x + t1 * av1.y;
    float p2 = t0 * av2.x + t1 * av2.y;
    float p3 = t0 * av3.x + t1 * av3.y;
    for (int off = 32; off >= 1; off >>= 1) {
      p0 += __shfl_xor(p0, off);
      p1 += __shfl_xor(p1, off);
      p2 += __shfl_xor(p2, off);
      p3 += __shfl_xor(p3, off);
    }
    if (l < 4) {
      float pw = (l == 0) ? p0 : (l == 1) ? p1 : (l == 2) ? p2 : p3;
      s[((size_t)l * 64 + b) * 512 + i0 + il] = pw;
    }
  }
  __syncthreads();
  int d = tid >> 1, hf = tid & 1;
  u32 wds[16];
#pragma unroll
  for (int k = 0; k < 16; ++k) {
    u32 lo = tile[32 * hf + 2 * k][d];
    u32 hi = tile[32 * hf + 2 * k + 1][d];
    wds[k] = lo | (hi << 16);
  }
  uint4* dst = (uint4*)(h16T + ((size_t)b * 128 + d) * 512 + i0 + 32 * hf);
  dst[0] = make_uint4(wds[0], wds[1], wds[2], wds[3]);
  dst[1] = make_uint4(wds[4], wds[5], wds[6], wds[7]);
  dst[2] = make_uint4(wds[8], wds[9], wds[10], wds[11]);
  dst[3] = make_uint4(wds[12], wds[13], wds[14], wds[15]);
}

// ---------------- Kernel C: fused attention, 32-j tiles, 4 waves/SIMD ----------------
// Block = 4 waves, 16-row i-tile; wave jq owns j-quarter as 4 t-iters of 32 j.
// R25 = R23 with accum halved: ks-outer QK over head-PAIRS (qk[2][2]=16 accum/pass).
// Accum total 48 (pv 32 + qk 16), arch cap 80 at (256,4) -> real slack, no spill.
__global__ __launch_bounds__(256, 4) void k_attn(const u16* __restrict__ h16,
                                                 const u16* __restrict__ h16T,
                                                 const float* __restrict__ s,
                                                 const int* __restrict__ adj,
                                                 const float* __restrict__ a0,
                                                 const float* __restrict__ a1,
                                                 const float* __restrict__ a2,
                                                 const float* __restrict__ a3,
                                                 float* __restrict__ out) {
  int bid = blockIdx.x;
  int wg = (bid & 7) * 256 + (bid >> 3);  // XCD swizzle (2048 % 8 == 0, bijective)
  int b = wg >> 5, i0r = (wg & 31) * 16;
  int tid = threadIdx.x, jq = tid >> 6, l = tid & 63;
  int l15 = l & 15, l4 = l >> 4;

  __shared__ u16 a16[4][128];       // 1 KB
  __shared__ float s_lds[4][512];   // 8 KB
  __shared__ u16 hrow[16][136];     // i-tile h16 rows, padded (4.25 KB)
  __shared__ u16 pbuf[4][16][40];   // per-wave P tile (5 KB)
  __shared__ u16 mrg_h[4][16][136]; // pv publish in f16 (17.4 KB)
  __shared__ float mml[4][16][2];   // 0.5 KB

  const size_t hb16 = (size_t)b * 512 * 128;
  const size_t hTb = (size_t)b * 128 * 512;

  // cooperative staging: a vectors, s rows, i-tile h rows
  if (tid < 128) {
    a16[0][tid] = __builtin_bit_cast(u16, (_Float16)a0[tid]);
    a16[1][tid] = __builtin_bit_cast(u16, (_Float16)a1[tid]);
    a16[2][tid] = __builtin_bit_cast(u16, (_Float16)a2[tid]);
    a16[3][tid] = __builtin_bit_cast(u16, (_Float16)a3[tid]);
  }
#pragma unroll
  for (int p = 0; p < 2; ++p) {
    int cid = p * 256 + tid;  // [0,512)
    int hd = cid >> 7, i4 = (cid & 127) * 4;
    *(float4*)&s_lds[hd][i4] = *(const float4*)(s + ((size_t)hd * 64 + b) * 512 + i4);
  }
  {
    int row = tid >> 4, ch = tid & 15;  // 256 threads = 16 rows x 16 chunks
    *(uint4*)&hrow[row][ch * 8] = *(const uint4*)(h16 + hb16 + (size_t)(i0r + row) * 128 + ch * 8);
  }
  __syncthreads();

  float m[4], lsum[4];
#pragma unroll
  for (int e = 0; e < 4; ++e) { m[e] = MASKV; lsum[e] = 0.f; }
  floatx4 pv[8];
#pragma unroll
  for (int dt = 0; dt < 8; ++dt) pv[dt] = (floatx4){0.f, 0.f, 0.f, 0.f};

  for (int t = 0; t < 4; ++t) {
    const int j0 = jq * 128 + 32 * t;

    // ---- adj values for this 16x32 tile ----
    int av[2][4];
#pragma unroll
    for (int e = 0; e < 4; ++e) {
      const int* ar = adj + ((size_t)(b * 512 + i0r + 4 * l4 + e)) * 512 + j0 + l15;
      av[0][e] = ar[0];
      av[1][e] = ar[16];
    }

    float x[2][4];
#pragma unroll
    for (int C = 0; C < 2; ++C)
#pragma unroll
      for (int e = 0; e < 4; ++e) x[C][e] = MASKV;

    // ---- two head-pair passes: ks outer, kfa transient (8 regs) ----
    for (int hp = 0; hp < 2; ++hp) {
      floatx4 qk[2][2];
#pragma unroll
      for (int hh = 0; hh < 2; ++hh) {
        qk[hh][0] = (floatx4){0.f, 0.f, 0.f, 0.f};
        qk[hh][1] = (floatx4){0.f, 0.f, 0.f, 0.f};
      }
#pragma unroll
      for (int ks = 0; ks < 4; ++ks) {
        half8 kf0 = *(const half8*)(h16 + hb16 + (size_t)(j0 + l15) * 128 + ks * 32 + 8 * l4);
        half8 kf1 = *(const half8*)(h16 + hb16 + (size_t)(j0 + 16 + l15) * 128 + ks * 32 + 8 * l4);
        half8 hfr = *(const half8*)((const char*)&hrow[0][0] + l15 * 272 + ks * 64 + l4 * 16);
        __builtin_amdgcn_s_setprio(1);
#pragma unroll
        for (int hh = 0; hh < 2; ++hh) {
          half8 af = *(const half8*)&a16[2 * hp + hh][ks * 32 + 8 * l4];
          half8 q = hfr * af;
          qk[hh][0] = __builtin_amdgcn_mfma_f32_16x16x32_f16(q, kf0, qk[hh][0], 0, 0, 0);
          qk[hh][1] = __builtin_amdgcn_mfma_f32_16x16x32_f16(q, kf1, qk[hh][1], 0, 0, 0);
        }
        __builtin_amdgcn_s_setprio(0);
      }
      // select for these two heads
#pragma unroll
      for (int hh = 0; hh < 2; ++hh) {
        int hd = 2 * hp + hh;
#pragma unroll
        for (int C = 0; C < 2; ++C) {
          float sjh = s_lds[hd][j0 + 16 * C + l15];
#pragma unroll
          for (int e = 0; e < 4; ++e) {
            if (av[C][e] == hd + 1) {
              float v = qk[hh][C][e] + s_lds[hd][i0r + 4 * l4 + e] + sjh;
              x[C][e] = (v > 0.f) ? v : LEAKY * v;
            }
          }
        }
      }
    }

    // ---- V fragments (PV B-operand) ----
    half8 vba[8];
#pragma unroll
    for (int dt = 0; dt < 8; ++dt)
      vba[dt] = *(const half8*)(h16T + hTb + (size_t)(16 * dt + l15) * 512 + j0 + 8 * l4);

    // ---- online softmax (rows r = 4*l4+e) ----
#pragma unroll
    for (int e = 0; e < 4; ++e) {
      float tmax = fmaxf(x[0][e], x[1][e]);
      tmax = fmaxf(tmax, __shfl_xor(tmax, 1));
      tmax = fmaxf(tmax, __shfl_xor(tmax, 2));
      tmax = fmaxf(tmax, __shfl_xor(tmax, 4));
      tmax = fmaxf(tmax, __shfl_xor(tmax, 8));
      float mn = fmaxf(m[e], tmax);
      float sc = __expf(m[e] - mn);
      float p0 = __expf(x[0][e] - mn);
      float p1 = __expf(x[1][e] - mn);
      float ls = p0 + p1;
      ls += __shfl_xor(ls, 1);
      ls += __shfl_xor(ls, 2);
      ls += __shfl_xor(ls, 4);
      ls += __shfl_xor(ls, 8);
      lsum[e] = lsum[e] * sc + ls;
      m[e] = mn;
#pragma unroll
      for (int dt = 0; dt < 8; ++dt) pv[dt][e] *= sc;
      int r = 4 * l4 + e;
      pbuf[jq][r][0 + l15] = __builtin_bit_cast(u16, (_Float16)p0);
      pbuf[jq][r][16 + l15] = __builtin_bit_cast(u16, (_Float16)p1);
    }

    asm volatile("s_waitcnt lgkmcnt(0)" ::: "memory");
    __builtin_amdgcn_sched_barrier(0);

    // ---- PV: A = P (row=l15 -> i, k=8*l4+e -> j), B = vba ----
    half8 pa = *(const half8*)((const char*)&pbuf[jq][0][0] + l15 * 80 + l4 * 16);
    __builtin_amdgcn_s_setprio(1);
#pragma unroll
    for (int dt = 0; dt < 8; ++dt)
      pv[dt] = __builtin_amdgcn_mfma_f32_16x16x32_f16(pa, vba[dt], pv[dt], 0, 0, 0);
    __builtin_amdgcn_s_setprio(0);
  }

  // ---- publish (f16): row = 4*l4+e -> i, col = 16dt+l15 -> d ----
#pragma unroll
  for (int dt = 0; dt < 8; ++dt)
#pragma unroll
    for (int e = 0; e < 4; ++e)
      mrg_h[jq][4 * l4 + e][16 * dt + l15] = __builtin_bit_cast(u16, (_Float16)pv[dt][e]);
  if (l15 == 0) {
#pragma unroll
    for (int e = 0; e < 4; ++e) {
      mml[jq][4 * l4 + e][0] = m[e];
      mml[jq][4 * l4 + e][1] = lsum[e];
    }
  }
  __syncthreads();

  // ---- cooperative 4-way merge + coalesced write (all 256 threads) ----
  for (int p2 = 0; p2 < 2; ++p2) {
    int i = (tid >> 5) + 8 * p2;
    int dc = (tid & 31) * 4;
    float m0 = mml[0][i][0], m1 = mml[1][i][0], m2 = mml[2][i][0], m3 = mml[3][i][0];
    float M = fmaxf(fmaxf(m0, m1), fmaxf(m2, m3));
    float w0 = __expf(m0 - M), w1 = __expf(m1 - M), w2 = __expf(m2 - M), w3 = __expf(m3 - M);
    float L = mml[0][i][1] * w0 + mml[1][i][1] * w1 + mml[2][i][1] * w2 + mml[3][i][1] * w3;
    float inv = 1.0f / L;
    w0 *= inv; w1 *= inv; w2 *= inv; w3 *= inv;
    float4 o = make_float4(0.f, 0.f, 0.f, 0.f);
    const float wq[4] = {w0, w1, w2, w3};
#pragma unroll
    for (int q = 0; q < 4; ++q) {
      ushort4 hv = *(const ushort4*)&mrg_h[q][i][dc];
      o.x += wq[q] * (float)__builtin_bit_cast(_Float16, hv.x);
      o.y += wq[q] * (float)__builtin_bit_cast(_Float16, hv.y);
      o.z += wq[q] * (float)__builtin_bit_cast(_Float16, hv.z);
      o.w += wq[q] * (float)__builtin_bit_cast(_Float16, hv.w);
    }
    *(float4*)(out + ((size_t)b * 512 + i0r + i) * 128 + dc) = o;
  }
}

extern "C" void kernel_launch(void* const* d_in, const int* in_sizes, int n_in,
                              void* d_out, int out_size, void* d_ws, size_t ws_size,
                              hipStream_t stream) {
  const float* hl = (const float*)d_in[0];
  const float* ht = (const float*)d_in[1];
  const float* ie = (const float*)d_in[2];
  const float* h  = (const float*)d_in[3];
  const int* adj  = (const int*)d_in[4];
  const float* wd = (const float*)d_in[5];
  const float* a0 = (const float*)d_in[6];
  const float* a1 = (const float*)d_in[7];
  const float* a2 = (const float*)d_in[8];
  const float* a3 = (const float*)d_in[9];

  // ws layout (~16.6 MB)
  float* hds  = (float*)d_ws;                   // 32 KB
  float* s    = (float*)((char*)d_ws + 32768);  // [4][64][512] = 512 KB
  u16* h16    = (u16*)((char*)d_ws + 557056);   // 8 MB
  u16* h16T   = (u16*)((char*)d_ws + 8945664);  // 8 MB
  float* o    = (float*)d_out;

  k_hds<<<64, 256, 0, stream>>>(hl, ht, ie, wd, hds);
  k_prep<<<512, 256, 0, stream>>>(h, hds, a0, a1, a2, a3, s, h16, h16T);
  k_attn<<<2048, 256, 0, stream>>>(h16, h16T, s, adj, a0, a1, a2, a3, o);
}

// Round 26
// 99.876 us; speedup vs baseline: 1.1092x; 1.1092x over previous
//
#include <hip/hip_runtime.h>
#include <hip/hip_bf16.h>
#include <hip/hip_fp16.h>

typedef _Float16 half8 __attribute__((ext_vector_type(8)));
typedef float floatx4 __attribute__((ext_vector_type(4)));
typedef unsigned short u16;
typedef unsigned int u32;
typedef unsigned long long u64;

#define LEAKY 0.2f
#define MASKV -9.0e15f

// ---------------- Kernel A: h_ds[b][d] = (mean of 150 rows) @ wd ----------------
__global__ __launch_bounds__(256) void k_hds(const float* __restrict__ hl,
                                             const float* __restrict__ ht,
                                             const float* __restrict__ ie,
                                             const float* __restrict__ wd,
                                             float* __restrict__ hds) {
  int b = blockIdx.x, tid = threadIdx.x;
  int d = tid & 127, hh = tid >> 7;
  __shared__ float pa_[2][128];
  __shared__ float ml[128];
  __shared__ float pb_[2][128];
  const size_t base = (size_t)b * 50 * 128 + d;
  float acc = 0.f;
  for (int r = hh * 25; r < hh * 25 + 25; ++r) {
    size_t o = base + (size_t)r * 128;
    acc += hl[o] + ht[o] + ie[o];
  }
  pa_[hh][d] = acc;
  __syncthreads();
  if (hh == 0) ml[d] = (pa_[0][d] + pa_[1][d]) * (1.0f / 150.0f);
  __syncthreads();
  float o = 0.f;
  for (int k = hh * 64; k < hh * 64 + 64; ++k) o = fmaf(ml[k], wd[k * 128 + d], o);
  pb_[hh][d] = o;
  __syncthreads();
  if (hh == 0) hds[b * 128 + d] = pb_[0][d] + pb_[1][d];
}

// ---------------- Kernel B: s[w][b][i], h16[b][i][d], h16T[b][d][i] ----------------
__global__ __launch_bounds__(256) void k_prep(const float* __restrict__ h,
                                              const float* __restrict__ hds,
                                              const float* __restrict__ a0,
                                              const float* __restrict__ a1,
                                              const float* __restrict__ a2,
                                              const float* __restrict__ a3,
                                              float* __restrict__ s,
                                              u16* __restrict__ h16,
                                              u16* __restrict__ h16T) {
  int b = blockIdx.x >> 3, i0 = (blockIdx.x & 7) * 64;
  int tid = threadIdx.x, w = tid >> 6, l = tid & 63;
  __shared__ u16 tile[64][130];
  int d0 = 2 * l;
  float2 hd2 = *(const float2*)(hds + b * 128 + d0);
  float2 av0 = *(const float2*)(a0 + d0);
  float2 av1 = *(const float2*)(a1 + d0);
  float2 av2 = *(const float2*)(a2 + d0);
  float2 av3 = *(const float2*)(a3 + d0);
  for (int rr = 0; rr < 16; ++rr) {
    int il = rr * 4 + w;
    size_t row = (size_t)b * 512 + i0 + il;
    float2 hv = *(const float2*)(h + row * 128 + d0);
    _Float16 f0 = (_Float16)hv.x, f1 = (_Float16)hv.y;
    u16 u0 = __builtin_bit_cast(u16, f0), u1 = __builtin_bit_cast(u16, f1);
    tile[il][d0] = u0;
    tile[il][d0 + 1] = u1;
    *(u32*)(h16 + row * 128 + d0) = (u32)u0 | ((u32)u1 << 16);
    float t0 = hv.x * hd2.x, t1 = hv.y * hd2.y;
    float p0 = t0 * av0.x + t1 * av0.y;
    float p1 = t0 * av1.x + t1 * av1.y;
    float p2 = t0 * av2.x + t1 * av2.y;
    float p3 = t0 * av3.x + t1 * av3.y;
    for (int off = 32; off >= 1; off >>= 1) {
      p0 += __shfl_xor(p0, off);
      p1 += __shfl_xor(p1, off);
      p2 += __shfl_xor(p2, off);
      p3 += __shfl_xor(p3, off);
    }
    if (l < 4) {
      float pw = (l == 0) ? p0 : (l == 1) ? p1 : (l == 2) ? p2 : p3;
      s[((size_t)l * 64 + b) * 512 + i0 + il] = pw;
    }
  }
  __syncthreads();
  int d = tid >> 1, hf = tid & 1;
  u32 wds[16];
#pragma unroll
  for (int k = 0; k < 16; ++k) {
    u32 lo = tile[32 * hf + 2 * k][d];
    u32 hi = tile[32 * hf + 2 * k + 1][d];
    wds[k] = lo | (hi << 16);
  }
  uint4* dst = (uint4*)(h16T + ((size_t)b * 128 + d) * 512 + i0 + 32 * hf);
  dst[0] = make_uint4(wds[0], wds[1], wds[2], wds[3]);
  dst[1] = make_uint4(wds[4], wds[5], wds[6], wds[7]);
  dst[2] = make_uint4(wds[8], wds[9], wds[10], wds[11]);
  dst[3] = make_uint4(wds[12], wds[13], wds[14], wds[15]);
}

// ---------------- Kernel C: fused attention, 32-j tiles, 4 waves/SIMD ----------------
// R26 = R23 + arch-register diet: adj values packed 4-bit into ct[2] (2 regs vs 8).
// ks-outer QK (kfa transient), qk[4][2]+pv = 64 accum; hrow/f16-merge LDS diet; (256,4).
__global__ __launch_bounds__(256, 4) void k_attn(const u16* __restrict__ h16,
                                                 const u16* __restrict__ h16T,
                                                 const float* __restrict__ s,
                                                 const int* __restrict__ adj,
                                                 const float* __restrict__ a0,
                                                 const float* __restrict__ a1,
                                                 const float* __restrict__ a2,
                                                 const float* __restrict__ a3,
                                                 float* __restrict__ out) {
  int bid = blockIdx.x;
  int wg = (bid & 7) * 256 + (bid >> 3);  // XCD swizzle (2048 % 8 == 0, bijective)
  int b = wg >> 5, i0r = (wg & 31) * 16;
  int tid = threadIdx.x, jq = tid >> 6, l = tid & 63;
  int l15 = l & 15, l4 = l >> 4;

  __shared__ u16 a16[4][128];       // 1 KB
  __shared__ float s_lds[4][512];   // 8 KB
  __shared__ u16 hrow[16][136];     // i-tile h16 rows, padded (4.25 KB)
  __shared__ u16 pbuf[4][16][40];   // per-wave P tile (5 KB)
  __shared__ u16 mrg_h[4][16][136]; // pv publish in f16 (17.4 KB)
  __shared__ float mml[4][16][2];   // 0.5 KB

  const size_t hb16 = (size_t)b * 512 * 128;
  const size_t hTb = (size_t)b * 128 * 512;

  // cooperative staging: a vectors, s rows, i-tile h rows
  if (tid < 128) {
    a16[0][tid] = __builtin_bit_cast(u16, (_Float16)a0[tid]);
    a16[1][tid] = __builtin_bit_cast(u16, (_Float16)a1[tid]);
    a16[2][tid] = __builtin_bit_cast(u16, (_Float16)a2[tid]);
    a16[3][tid] = __builtin_bit_cast(u16, (_Float16)a3[tid]);
  }
#pragma unroll
  for (int p = 0; p < 2; ++p) {
    int cid = p * 256 + tid;  // [0,512)
    int hd = cid >> 7, i4 = (cid & 127) * 4;
    *(float4*)&s_lds[hd][i4] = *(const float4*)(s + ((size_t)hd * 64 + b) * 512 + i4);
  }
  {
    int row = tid >> 4, ch = tid & 15;  // 256 threads = 16 rows x 16 chunks
    *(uint4*)&hrow[row][ch * 8] = *(const uint4*)(h16 + hb16 + (size_t)(i0r + row) * 128 + ch * 8);
  }
  __syncthreads();

  float m[4], lsum[4];
#pragma unroll
  for (int e = 0; e < 4; ++e) { m[e] = MASKV; lsum[e] = 0.f; }
  floatx4 pv[8];
#pragma unroll
  for (int dt = 0; dt < 8; ++dt) pv[dt] = (floatx4){0.f, 0.f, 0.f, 0.f};

  for (int t = 0; t < 4; ++t) {
    const int j0 = jq * 128 + 32 * t;

    // ---- adj values packed 4-bit: ct[C] bits [4e..4e+3] = adj value for row e ----
    u32 ct[2] = {0u, 0u};
#pragma unroll
    for (int e = 0; e < 4; ++e) {
      const int* ar = adj + ((size_t)(b * 512 + i0r + 4 * l4 + e)) * 512 + j0 + l15;
      ct[0] |= ((u32)ar[0] & 0xF) << (4 * e);
      ct[1] |= ((u32)ar[16] & 0xF) << (4 * e);
    }

    // ---- QK: ks outer (kfa transient 8 regs), hd inner; qk[4][2] accum ----
    floatx4 qk[4][2];
#pragma unroll
    for (int hd = 0; hd < 4; ++hd) {
      qk[hd][0] = (floatx4){0.f, 0.f, 0.f, 0.f};
      qk[hd][1] = (floatx4){0.f, 0.f, 0.f, 0.f};
    }
#pragma unroll
    for (int ks = 0; ks < 4; ++ks) {
      half8 kf0 = *(const half8*)(h16 + hb16 + (size_t)(j0 + l15) * 128 + ks * 32 + 8 * l4);
      half8 kf1 = *(const half8*)(h16 + hb16 + (size_t)(j0 + 16 + l15) * 128 + ks * 32 + 8 * l4);
      half8 hfr = *(const half8*)((const char*)&hrow[0][0] + l15 * 272 + ks * 64 + l4 * 16);
      __builtin_amdgcn_s_setprio(1);
#pragma unroll
      for (int hd = 0; hd < 4; ++hd) {
        half8 af = *(const half8*)&a16[hd][ks * 32 + 8 * l4];
        half8 q = hfr * af;
        qk[hd][0] = __builtin_amdgcn_mfma_f32_16x16x32_f16(q, kf0, qk[hd][0], 0, 0, 0);
        qk[hd][1] = __builtin_amdgcn_mfma_f32_16x16x32_f16(q, kf1, qk[hd][1], 0, 0, 0);
      }
      __builtin_amdgcn_s_setprio(0);
    }

    // ---- select + leaky relu, merge heads ----
    float x[2][4];
#pragma unroll
    for (int C = 0; C < 2; ++C)
#pragma unroll
      for (int e = 0; e < 4; ++e) x[C][e] = MASKV;
#pragma unroll
    for (int hd = 0; hd < 4; ++hd) {
#pragma unroll
      for (int C = 0; C < 2; ++C) {
        float sjh = s_lds[hd][j0 + 16 * C + l15];
#pragma unroll
        for (int e = 0; e < 4; ++e) {
          if (((ct[C] >> (4 * e)) & 0xF) == (u32)(hd + 1)) {
            float v = qk[hd][C][e] + s_lds[hd][i0r + 4 * l4 + e] + sjh;
            x[C][e] = (v > 0.f) ? v : LEAKY * v;
          }
        }
      }
    }

    // ---- V fragments (PV B-operand) ----
    half8 vba[8];
#pragma unroll
    for (int dt = 0; dt < 8; ++dt)
      vba[dt] = *(const half8*)(h16T + hTb + (size_t)(16 * dt + l15) * 512 + j0 + 8 * l4);

    // ---- online softmax (rows r = 4*l4+e) ----
#pragma unroll
    for (int e = 0; e < 4; ++e) {
      float tmax = fmaxf(x[0][e], x[1][e]);
      tmax = fmaxf(tmax, __shfl_xor(tmax, 1));
      tmax = fmaxf(tmax, __shfl_xor(tmax, 2));
      tmax = fmaxf(tmax, __shfl_xor(tmax, 4));
      tmax = fmaxf(tmax, __shfl_xor(tmax, 8));
      float mn = fmaxf(m[e], tmax);
      float sc = __expf(m[e] - mn);
      float p0 = __expf(x[0][e] - mn);
      float p1 = __expf(x[1][e] - mn);
      float ls = p0 + p1;
      ls += __shfl_xor(ls, 1);
      ls += __shfl_xor(ls, 2);
      ls += __shfl_xor(ls, 4);
      ls += __shfl_xor(ls, 8);
      lsum[e] = lsum[e] * sc + ls;
      m[e] = mn;
#pragma unroll
      for (int dt = 0; dt < 8; ++dt) pv[dt][e] *= sc;
      int r = 4 * l4 + e;
      pbuf[jq][r][0 + l15] = __builtin_bit_cast(u16, (_Float16)p0);
      pbuf[jq][r][16 + l15] = __builtin_bit_cast(u16, (_Float16)p1);
    }

    asm volatile("s_waitcnt lgkmcnt(0)" ::: "memory");
    __builtin_amdgcn_sched_barrier(0);

    // ---- PV: A = P, B = vba ----
    half8 pa = *(const half8*)((const char*)&pbuf[jq][0][0] + l15 * 80 + l4 * 16);
    __builtin_amdgcn_s_setprio(1);
#pragma unroll
    for (int dt = 0; dt < 8; ++dt)
      pv[dt] = __builtin_amdgcn_mfma_f32_16x16x32_f16(pa, vba[dt], pv[dt], 0, 0, 0);
    __builtin_amdgcn_s_setprio(0);
  }

  // ---- publish (f16): row = 4*l4+e -> i, col = 16dt+l15 -> d ----
#pragma unroll
  for (int dt = 0; dt < 8; ++dt)
#pragma unroll
    for (int e = 0; e < 4; ++e)
      mrg_h[jq][4 * l4 + e][16 * dt + l15] = __builtin_bit_cast(u16, (_Float16)pv[dt][e]);
  if (l15 == 0) {
#pragma unroll
    for (int e = 0; e < 4; ++e) {
      mml[jq][4 * l4 + e][0] = m[e];
      mml[jq][4 * l4 + e][1] = lsum[e];
    }
  }
  __syncthreads();

  // ---- cooperative 4-way merge + coalesced write (all 256 threads) ----
  for (int p2 = 0; p2 < 2; ++p2) {
    int i = (tid >> 5) + 8 * p2;
    int dc = (tid & 31) * 4;
    float m0 = mml[0][i][0], m1 = mml[1][i][0], m2 = mml[2][i][0], m3 = mml[3][i][0];
    float M = fmaxf(fmaxf(m0, m1), fmaxf(m2, m3));
    float w0 = __expf(m0 - M), w1 = __expf(m1 - M), w2 = __expf(m2 - M), w3 = __expf(m3 - M);
    float L = mml[0][i][1] * w0 + mml[1][i][1] * w1 + mml[2][i][1] * w2 + mml[3][i][1] * w3;
    float inv = 1.0f / L;
    w0 *= inv; w1 *= inv; w2 *= inv; w3 *= inv;
    float4 o = make_float4(0.f, 0.f, 0.f, 0.f);
    const float wq[4] = {w0, w1, w2, w3};
#pragma unroll
    for (int q = 0; q < 4; ++q) {
      ushort4 hv = *(const ushort4*)&mrg_h[q][i][dc];
      o.x += wq[q] * (float)__builtin_bit_cast(_Float16, hv.x);
      o.y += wq[q] * (float)__builtin_bit_cast(_Float16, hv.y);
      o.z += wq[q] * (float)__builtin_bit_cast(_Float16, hv.z);
      o.w += wq[q] * (float)__builtin_bit_cast(_Float16, hv.w);
    }
    *(float4*)(out + ((size_t)b * 512 + i0r + i) * 128 + dc) = o;
  }
}

extern "C" void kernel_launch(void* const* d_in, const int* in_sizes, int n_in,
                              void* d_out, int out_size, void* d_ws, size_t ws_size,
                              hipStream_t stream) {
  const float* hl = (const float*)d_in[0];
  const float* ht = (const float*)d_in[1];
  const float* ie = (const float*)d_in[2];
  const float* h  = (const float*)d_in[3];
  const int* adj  = (const int*)d_in[4];
  const float* wd = (const float*)d_in[5];
  const float* a0 = (const float*)d_in[6];
  const float* a1 = (const float*)d_in[7];
  const float* a2 = (const float*)d_in[8];
  const float* a3 = (const float*)d_in[9];

  // ws layout (~16.6 MB)
  float* hds  = (float*)d_ws;                   // 32 KB
  float* s    = (float*)((char*)d_ws + 32768);  // [4][64][512] = 512 KB
  u16* h16    = (u16*)((char*)d_ws + 557056);   // 8 MB
  u16* h16T   = (u16*)((char*)d_ws + 8945664);  // 8 MB
  float* o    = (float*)d_out;

  k_hds<<<64, 256, 0, stream>>>(hl, ht, ie, wd, hds);
  k_prep<<<512, 256, 0, stream>>>(h, hds, a0, a1, a2, a3, s, h16, h16T);
  k_attn<<<2048, 256, 0, stream>>>(h16, h16T, s, adj, a0, a1, a2, a3, o);
}

// Round 27
// 98.192 us; speedup vs baseline: 1.1282x; 1.0171x over previous
//
#include <hip/hip_runtime.h>
#include <hip/hip_bf16.h>
#include <hip/hip_fp16.h>

typedef _Float16 half8 __attribute__((ext_vector_type(8)));
typedef float floatx4 __attribute__((ext_vector_type(4)));
typedef unsigned short u16;
typedef unsigned int u32;
typedef unsigned long long u64;

#define LEAKY 0.2f
#define MASKV -9.0e15f

// ---------------- Kernel A: h_ds[b][d] = (mean of 150 rows) @ wd ----------------
__global__ __launch_bounds__(256) void k_hds(const float* __restrict__ hl,
                                             const float* __restrict__ ht,
                                             const float* __restrict__ ie,
                                             const float* __restrict__ wd,
                                             float* __restrict__ hds) {
  int b = blockIdx.x, tid = threadIdx.x;
  int d = tid & 127, hh = tid >> 7;
  __shared__ float pa_[2][128];
  __shared__ float ml[128];
  __shared__ float pb_[2][128];
  const size_t base = (size_t)b * 50 * 128 + d;
  float acc = 0.f;
  for (int r = hh * 25; r < hh * 25 + 25; ++r) {
    size_t o = base + (size_t)r * 128;
    acc += hl[o] + ht[o] + ie[o];
  }
  pa_[hh][d] = acc;
  __syncthreads();
  if (hh == 0) ml[d] = (pa_[0][d] + pa_[1][d]) * (1.0f / 150.0f);
  __syncthreads();
  float o = 0.f;
  for (int k = hh * 64; k < hh * 64 + 64; ++k) o = fmaf(ml[k], wd[k * 128 + d], o);
  pb_[hh][d] = o;
  __syncthreads();
  if (hh == 0) hds[b * 128 + d] = pb_[0][d] + pb_[1][d];
}

// ---------------- Kernel B: s[w][b][i], h16[b][i][d], h16T[b][d][i] ----------------
__global__ __launch_bounds__(256) void k_prep(const float* __restrict__ h,
                                              const float* __restrict__ hds,
                                              const float* __restrict__ a0,
                                              const float* __restrict__ a1,
                                              const float* __restrict__ a2,
                                              const float* __restrict__ a3,
                                              float* __restrict__ s,
                                              u16* __restrict__ h16,
                                              u16* __restrict__ h16T) {
  int b = blockIdx.x >> 3, i0 = (blockIdx.x & 7) * 64;
  int tid = threadIdx.x, w = tid >> 6, l = tid & 63;
  __shared__ u16 tile[64][130];
  int d0 = 2 * l;
  float2 hd2 = *(const float2*)(hds + b * 128 + d0);
  float2 av0 = *(const float2*)(a0 + d0);
  float2 av1 = *(const float2*)(a1 + d0);
  float2 av2 = *(const float2*)(a2 + d0);
  float2 av3 = *(const float2*)(a3 + d0);
  for (int rr = 0; rr < 16; ++rr) {
    int il = rr * 4 + w;
    size_t row = (size_t)b * 512 + i0 + il;
    float2 hv = *(const float2*)(h + row * 128 + d0);
    _Float16 f0 = (_Float16)hv.x, f1 = (_Float16)hv.y;
    u16 u0 = __builtin_bit_cast(u16, f0), u1 = __builtin_bit_cast(u16, f1);
    tile[il][d0] = u0;
    tile[il][d0 + 1] = u1;
    *(u32*)(h16 + row * 128 + d0) = (u32)u0 | ((u32)u1 << 16);
    float t0 = hv.x * hd2.x, t1 = hv.y * hd2.y;
    float p0 = t0 * av0.x + t1 * av0.y;
    float p1 = t0 * av1.x + t1 * av1.y;
    float p2 = t0 * av2.x + t1 * av2.y;
    float p3 = t0 * av3.x + t1 * av3.y;
    for (int off = 32; off >= 1; off >>= 1) {
      p0 += __shfl_xor(p0, off);
      p1 += __shfl_xor(p1, off);
      p2 += __shfl_xor(p2, off);
      p3 += __shfl_xor(p3, off);
    }
    if (l < 4) {
      float pw = (l == 0) ? p0 : (l == 1) ? p1 : (l == 2) ? p2 : p3;
      s[((size_t)l * 64 + b) * 512 + i0 + il] = pw;
    }
  }
  __syncthreads();
  int d = tid >> 1, hf = tid & 1;
  u32 wds[16];
#pragma unroll
  for (int k = 0; k < 16; ++k) {
    u32 lo = tile[32 * hf + 2 * k][d];
    u32 hi = tile[32 * hf + 2 * k + 1][d];
    wds[k] = lo | (hi << 16);
  }
  uint4* dst = (uint4*)(h16T + ((size_t)b * 128 + d) * 512 + i0 + 32 * hf);
  dst[0] = make_uint4(wds[0], wds[1], wds[2], wds[3]);
  dst[1] = make_uint4(wds[4], wds[5], wds[6], wds[7]);
  dst[2] = make_uint4(wds[8], wds[9], wds[10], wds[11]);
  dst[3] = make_uint4(wds[12], wds[13], wds[14], wds[15]);
}

// ---------------- Kernel C: fused attention, 32-j tiles, 4 waves/SIMD (best: R23) ----------------
// Block = 4 waves, 16-row i-tile; wave jq owns j-quarter as 4 t-iters of 32 j.
// (256,4): ks-outer QK (kfa transient; qk[4][2] accum), h-fragments from LDS (hrow),
// merge buffer published in f16 (LDS 36.4 KB -> 4 blocks/CU).
__global__ __launch_bounds__(256, 4) void k_attn(const u16* __restrict__ h16,
                                                 const u16* __restrict__ h16T,
                                                 const float* __restrict__ s,
                                                 const int* __restrict__ adj,
                                                 const float* __restrict__ a0,
                                                 const float* __restrict__ a1,
                                                 const float* __restrict__ a2,
                                                 const float* __restrict__ a3,
                                                 float* __restrict__ out) {
  int bid = blockIdx.x;
  int wg = (bid & 7) * 256 + (bid >> 3);  // XCD swizzle (2048 % 8 == 0, bijective)
  int b = wg >> 5, i0r = (wg & 31) * 16;
  int tid = threadIdx.x, jq = tid >> 6, l = tid & 63;
  int l15 = l & 15, l4 = l >> 4;

  __shared__ u16 a16[4][128];       // 1 KB
  __shared__ float s_lds[4][512];   // 8 KB
  __shared__ u16 hrow[16][136];     // i-tile h16 rows, padded (4.25 KB)
  __shared__ u16 pbuf[4][16][40];   // per-wave P tile (5 KB)
  __shared__ u16 mrg_h[4][16][136]; // pv publish in f16 (17.4 KB)
  __shared__ float mml[4][16][2];   // 0.5 KB

  const size_t hb16 = (size_t)b * 512 * 128;
  const size_t hTb = (size_t)b * 128 * 512;

  // cooperative staging: a vectors, s rows, i-tile h rows
  if (tid < 128) {
    a16[0][tid] = __builtin_bit_cast(u16, (_Float16)a0[tid]);
    a16[1][tid] = __builtin_bit_cast(u16, (_Float16)a1[tid]);
    a16[2][tid] = __builtin_bit_cast(u16, (_Float16)a2[tid]);
    a16[3][tid] = __builtin_bit_cast(u16, (_Float16)a3[tid]);
  }
#pragma unroll
  for (int p = 0; p < 2; ++p) {
    int cid = p * 256 + tid;  // [0,512)
    int hd = cid >> 7, i4 = (cid & 127) * 4;
    *(float4*)&s_lds[hd][i4] = *(const float4*)(s + ((size_t)hd * 64 + b) * 512 + i4);
  }
  {
    int row = tid >> 4, ch = tid & 15;  // 256 threads = 16 rows x 16 chunks
    *(uint4*)&hrow[row][ch * 8] = *(const uint4*)(h16 + hb16 + (size_t)(i0r + row) * 128 + ch * 8);
  }
  __syncthreads();

  float m[4], lsum[4];
#pragma unroll
  for (int e = 0; e < 4; ++e) { m[e] = MASKV; lsum[e] = 0.f; }
  floatx4 pv[8];
#pragma unroll
  for (int dt = 0; dt < 8; ++dt) pv[dt] = (floatx4){0.f, 0.f, 0.f, 0.f};

  for (int t = 0; t < 4; ++t) {
    const int j0 = jq * 128 + 32 * t;

    // ---- adj values for this 16x32 tile ----
    int av[2][4];
#pragma unroll
    for (int e = 0; e < 4; ++e) {
      const int* ar = adj + ((size_t)(b * 512 + i0r + 4 * l4 + e)) * 512 + j0 + l15;
      av[0][e] = ar[0];
      av[1][e] = ar[16];
    }

    // ---- QK: ks outer (kfa transient 8 regs), hd inner; qk[4][2] accum ----
    floatx4 qk[4][2];
#pragma unroll
    for (int hd = 0; hd < 4; ++hd) {
      qk[hd][0] = (floatx4){0.f, 0.f, 0.f, 0.f};
      qk[hd][1] = (floatx4){0.f, 0.f, 0.f, 0.f};
    }
#pragma unroll
    for (int ks = 0; ks < 4; ++ks) {
      half8 kf0 = *(const half8*)(h16 + hb16 + (size_t)(j0 + l15) * 128 + ks * 32 + 8 * l4);
      half8 kf1 = *(const half8*)(h16 + hb16 + (size_t)(j0 + 16 + l15) * 128 + ks * 32 + 8 * l4);
      half8 hfr = *(const half8*)((const char*)&hrow[0][0] + l15 * 272 + ks * 64 + l4 * 16);
      __builtin_amdgcn_s_setprio(1);
#pragma unroll
      for (int hd = 0; hd < 4; ++hd) {
        half8 af = *(const half8*)&a16[hd][ks * 32 + 8 * l4];
        half8 q = hfr * af;
        qk[hd][0] = __builtin_amdgcn_mfma_f32_16x16x32_f16(q, kf0, qk[hd][0], 0, 0, 0);
        qk[hd][1] = __builtin_amdgcn_mfma_f32_16x16x32_f16(q, kf1, qk[hd][1], 0, 0, 0);
      }
      __builtin_amdgcn_s_setprio(0);
    }

    // ---- select + leaky relu, merge heads ----
    float x[2][4];
#pragma unroll
    for (int C = 0; C < 2; ++C)
#pragma unroll
      for (int e = 0; e < 4; ++e) x[C][e] = MASKV;
#pragma unroll
    for (int hd = 0; hd < 4; ++hd) {
#pragma unroll
      for (int C = 0; C < 2; ++C) {
        float sjh = s_lds[hd][j0 + 16 * C + l15];
#pragma unroll
        for (int e = 0; e < 4; ++e) {
          if (av[C][e] == hd + 1) {
            float v = qk[hd][C][e] + s_lds[hd][i0r + 4 * l4 + e] + sjh;
            x[C][e] = (v > 0.f) ? v : LEAKY * v;
          }
        }
      }
    }

    // ---- V fragments (PV B-operand) ----
    half8 vba[8];
#pragma unroll
    for (int dt = 0; dt < 8; ++dt)
      vba[dt] = *(const half8*)(h16T + hTb + (size_t)(16 * dt + l15) * 512 + j0 + 8 * l4);

    // ---- online softmax ----
#pragma unroll
    for (int e = 0; e < 4; ++e) {
      float tmax = fmaxf(x[0][e], x[1][e]);
      tmax = fmaxf(tmax, __shfl_xor(tmax, 1));
      tmax = fmaxf(tmax, __shfl_xor(tmax, 2));
      tmax = fmaxf(tmax, __shfl_xor(tmax, 4));
      tmax = fmaxf(tmax, __shfl_xor(tmax, 8));
      float mn = fmaxf(m[e], tmax);
      float sc = __expf(m[e] - mn);
      float p0 = __expf(x[0][e] - mn);
      float p1 = __expf(x[1][e] - mn);
      float ls = p0 + p1;
      ls += __shfl_xor(ls, 1);
      ls += __shfl_xor(ls, 2);
      ls += __shfl_xor(ls, 4);
      ls += __shfl_xor(ls, 8);
      lsum[e] = lsum[e] * sc + ls;
      m[e] = mn;
#pragma unroll
      for (int dt = 0; dt < 8; ++dt) pv[dt][e] *= sc;
      int r = 4 * l4 + e;
      pbuf[jq][r][0 + l15] = __builtin_bit_cast(u16, (_Float16)p0);
      pbuf[jq][r][16 + l15] = __builtin_bit_cast(u16, (_Float16)p1);
    }

    asm volatile("s_waitcnt lgkmcnt(0)" ::: "memory");
    __builtin_amdgcn_sched_barrier(0);

    // ---- PV: A = P, B = vba ----
    half8 pa = *(const half8*)((const char*)&pbuf[jq][0][0] + l15 * 80 + l4 * 16);
    __builtin_amdgcn_s_setprio(1);
#pragma unroll
    for (int dt = 0; dt < 8; ++dt)
      pv[dt] = __builtin_amdgcn_mfma_f32_16x16x32_f16(pa, vba[dt], pv[dt], 0, 0, 0);
    __builtin_amdgcn_s_setprio(0);
  }

  // ---- publish (f16): row = 4*l4+e -> i, col = 16dt+l15 -> d ----
#pragma unroll
  for (int dt = 0; dt < 8; ++dt)
#pragma unroll
    for (int e = 0; e < 4; ++e)
      mrg_h[jq][4 * l4 + e][16 * dt + l15] = __builtin_bit_cast(u16, (_Float16)pv[dt][e]);
  if (l15 == 0) {
#pragma unroll
    for (int e = 0; e < 4; ++e) {
      mml[jq][4 * l4 + e][0] = m[e];
      mml[jq][4 * l4 + e][1] = lsum[e];
    }
  }
  __syncthreads();

  // ---- cooperative 4-way merge + coalesced write (all 256 threads) ----
  for (int p2 = 0; p2 < 2; ++p2) {
    int i = (tid >> 5) + 8 * p2;
    int dc = (tid & 31) * 4;
    float m0 = mml[0][i][0], m1 = mml[1][i][0], m2 = mml[2][i][0], m3 = mml[3][i][0];
    float M = fmaxf(fmaxf(m0, m1), fmaxf(m2, m3));
    float w0 = __expf(m0 - M), w1 = __expf(m1 - M), w2 = __expf(m2 - M), w3 = __expf(m3 - M);
    float L = mml[0][i][1] * w0 + mml[1][i][1] * w1 + mml[2][i][1] * w2 + mml[3][i][1] * w3;
    float inv = 1.0f / L;
    w0 *= inv; w1 *= inv; w2 *= inv; w3 *= inv;
    float4 o = make_float4(0.f, 0.f, 0.f, 0.f);
    const float wq[4] = {w0, w1, w2, w3};
#pragma unroll
    for (int q = 0; q < 4; ++q) {
      ushort4 hv = *(const ushort4*)&mrg_h[q][i][dc];
      o.x += wq[q] * (float)__builtin_bit_cast(_Float16, hv.x);
      o.y += wq[q] * (float)__builtin_bit_cast(_Float16, hv.y);
      o.z += wq[q] * (float)__builtin_bit_cast(_Float16, hv.z);
      o.w += wq[q] * (float)__builtin_bit_cast(_Float16, hv.w);
    }
    *(float4*)(out + ((size_t)b * 512 + i0r + i) * 128 + dc) = o;
  }
}

extern "C" void kernel_launch(void* const* d_in, const int* in_sizes, int n_in,
                              void* d_out, int out_size, void* d_ws, size_t ws_size,
                              hipStream_t stream) {
  const float* hl = (const float*)d_in[0];
  const float* ht = (const float*)d_in[1];
  const float* ie = (const float*)d_in[2];
  const float* h  = (const float*)d_in[3];
  const int* adj  = (const int*)d_in[4];
  const float* wd = (const float*)d_in[5];
  const float* a0 = (const float*)d_in[6];
  const float* a1 = (const float*)d_in[7];
  const float* a2 = (const float*)d_in[8];
  const float* a3 = (const float*)d_in[9];

  // ws layout (~16.6 MB)
  float* hds  = (float*)d_ws;                   // 32 KB
  float* s    = (float*)((char*)d_ws + 32768);  // [4][64][512] = 512 KB
  u16* h16    = (u16*)((char*)d_ws + 557056);   // 8 MB
  u16* h16T   = (u16*)((char*)d_ws + 8945664);  // 8 MB
  float* o    = (float*)d_out;

  k_hds<<<64, 256, 0, stream>>>(hl, ht, ie, wd, hds);
  k_prep<<<512, 256, 0, stream>>>(h, hds, a0, a1, a2, a3, s, h16, h16T);
  k_attn<<<2048, 256, 0, stream>>>(h16, h16T, s, adj, a0, a1, a2, a3, o);
}